// Round 1
// 322.053 us; speedup vs baseline: 1.0007x; 1.0007x over previous
//
#include <hip/hip_runtime.h>
#include <math.h>

#define NN 4096
#define PP 10
#define DD 17
#define DIM 300
#define NPD (NN * PP * DD)

// One wave per (n,p). Half-wave h handles rows k = 2i+h.
// v2: preload ALL 9 rows/half-wave into registers before reducing.
// Rationale: v1 had VGPR_Count=28 -> at most ~1 row of data in flight,
// 9 serialized {load -> wait -> shfl-chain} rounds per wave. All row
// addresses are known up front, so hoisting the 27 float4 loads gives
// continuous memory issue (~9x MLP/wave) at the cost of occupancy
// (3 waves/SIMD instead of ~6.6) -- a good trade while latency-bound.
__global__ __launch_bounds__(256, 3) void hs_fwd_kernel(
    const int* __restrict__ word_idx,   // [N]
    const int* __restrict__ paths,      // [N,P,D]
    const int* __restrict__ labels,     // [N,P,D]
    const float* __restrict__ emb1,     // [VOCAB, DIM]
    const float* __restrict__ emb2,     // [VOCAB-1, DIM]
    float* __restrict__ out,            // [N*P*D]
    float* __restrict__ target)         // [N*P*D]
{
    const int wave = (int)((blockIdx.x * blockDim.x + threadIdx.x) >> 6);
    const int lane = (int)(threadIdx.x & 63);
    if (wave >= NN * PP) return;
    const int n = wave / PP;
    const int j    = lane & 31;   // lane within half-wave
    const int half = lane >> 5;   // which half-wave (0/1)

    // proj[n] as float4 strided across the 32 lanes of each half-wave.
    // Rows are 1200 B (75 float4), 16B-aligned.
    const float4* p4 = (const float4*)(emb1 + (long long)word_idx[n] * DIM);
    const float4 pr0 = p4[j];
    const float4 pr1 = p4[j + 32];
    const float4 pr2 = (j < 11) ? p4[j + 64] : make_float4(0.f, 0.f, 0.f, 0.f);

    const long long base = (long long)wave * DD;
    const int my_path  = (lane < DD) ? paths[base + lane]  : 0;
    const int my_label = (lane < DD) ? labels[base + lane] : 0;

    // ---- Phase 1: issue all row loads (27 float4/lane in flight) ----
    float4 a0[9], a1[9], a2[9];
    #pragma unroll
    for (int i = 0; i < 9; ++i) {
        const int k  = 2 * i + half;
        const int kk = (k < DD) ? k : 16;   // half-1 i=8 is dead: alias row 16
                                            // (same addresses half-0 loads -> L1 hit, no extra fetch)
        const int row = __shfl(my_path, kk);
        const float4* r4 = (const float4*)(emb2 + (long long)row * DIM);
        a0[i] = r4[j];
        a1[i] = r4[j + 32];
        a2[i] = (j < 11) ? r4[j + 64] : make_float4(0.f, 0.f, 0.f, 0.f);
    }

    // ---- Phase 2: reduce ----
    float my_logit = 0.0f;
    #pragma unroll
    for (int i = 0; i < 9; ++i) {
        const int k = 2 * i + half;
        float acc = pr0.x * a0[i].x + pr0.y * a0[i].y + pr0.z * a0[i].z + pr0.w * a0[i].w
                  + pr1.x * a1[i].x + pr1.y * a1[i].y + pr1.z * a1[i].z + pr1.w * a1[i].w
                  + pr2.x * a2[i].x + pr2.y * a2[i].y + pr2.z * a2[i].z + pr2.w * a2[i].w;
        if (k >= DD) acc = 0.0f;            // zero the aliased dead row
        // butterfly within each 32-lane half
        #pragma unroll
        for (int off = 16; off > 0; off >>= 1)
            acc += __shfl_xor(acc, off);
        // exchange: half-0 lanes see half-1's row sum in `other`
        const float other = __shfl_xor(acc, 32);
        if (lane == 2 * i) my_logit = acc;                         // even row k=2i
        if (2 * i + 1 < DD && lane == 2 * i + 1) my_logit = other; // odd row k=2i+1
    }

    if (lane < DD) {
        const float o = 1.0f / (1.0f + expf(-my_logit));
        out[base + lane] = o;
        // mask == (sigmoid(logit) >= 0.5) == (logit >= 0): exact, no rounding
        const int mask = (my_logit >= 0.0f) ? 1 : 0;
        target[base + lane] = (mask == my_label) ? 1.0f : 0.0f;
    }
}

extern "C" void kernel_launch(void* const* d_in, const int* in_sizes, int n_in,
                              void* d_out, int out_size, void* d_ws, size_t ws_size,
                              hipStream_t stream) {
    const int*   word_idx = (const int*)d_in[0];
    const int*   paths    = (const int*)d_in[1];
    const int*   labels   = (const int*)d_in[2];
    const float* emb1     = (const float*)d_in[3];
    const float* emb2     = (const float*)d_in[4];

    float* out    = (float*)d_out;          // [N*P*D] sigmoid outputs
    float* target = (float*)d_out + NPD;    // [N*P*D] targets

    const int total_waves = NN * PP;        // one wave per (n,p)
    const int waves_per_block = 4;          // 256 threads
    const int blocks = (total_waves + waves_per_block - 1) / waves_per_block;

    hs_fwd_kernel<<<blocks, 256, 0, stream>>>(word_idx, paths, labels, emb1, emb2, out, target);
}